// Round 1
// baseline (419.884 us; speedup 1.0000x reference)
//
#include <hip/hip_runtime.h>
#include <math.h>

// Problem constants
#define BB 256
#define KK 32
#define DD 128
#define HH 256
#define NN 16
// d_out layout (fp32, concatenated in return order)
// m_ij:   [B,K,K,D] at O0
// alpha:  [B,K,K,N] at O1
// e_ij:   [B,K,K,D] at O2
// logits: [B,K,K,N] at O3
#define O0 ((size_t)0)
#define O1 ((size_t)33554432)
#define O2 ((size_t)37748736)
#define O3 ((size_t)71303168)

// ---------------------------------------------------------------------------
// Kernel A: Hi[bk][h] = sum_d z[bk][d] * W1[d][h]
//           Hj[bk][h] = sum_d z[bk][d] * W1[128+d][h]
// z: (8192,128), W1: (256,256) row-major. Output Hi,Hj: (8192,256) fp32 in ws.
// Grid: 512 blocks x 256 threads; block covers 16 bk-rows x 512 out-cols.
// Thread: 4 rows x 8 cols microtile.
// ---------------------------------------------------------------------------
__global__ __launch_bounds__(256) void hproj_kernel(
    const float* __restrict__ z, const float* __restrict__ W1,
    float* __restrict__ Hi, float* __restrict__ Hj) {
  __shared__ float sz[16][128];  // 8 KB
  const int tid = threadIdx.x;
  const int row0 = blockIdx.x * 16;

  // stage z tile: 2048 floats, 8 per thread
#pragma unroll
  for (int s = 0; s < 8; ++s) {
    int idx = tid + s * 256;
    int r = idx >> 7, c = idx & 127;
    sz[r][c] = z[(size_t)(row0 + r) * 128 + c];
  }
  __syncthreads();

  const int rg = tid >> 6;  // 0..3 -> rows rg*4..+3 (uniform per wave -> LDS broadcast)
  const int cg = tid & 63;  // 0..63 -> cols cg*8..+7
  const float* wbase = (cg < 32) ? (W1 + cg * 8) : (W1 + 128 * 256 + (cg - 32) * 8);

  float4 acc[4][2];
#pragma unroll
  for (int r = 0; r < 4; ++r) {
    acc[r][0] = make_float4(0.f, 0.f, 0.f, 0.f);
    acc[r][1] = make_float4(0.f, 0.f, 0.f, 0.f);
  }

  for (int d = 0; d < 128; ++d) {
    float4 w0 = *(const float4*)(wbase + (size_t)d * 256);
    float4 w1 = *(const float4*)(wbase + (size_t)d * 256 + 4);
#pragma unroll
    for (int r = 0; r < 4; ++r) {
      float a = sz[rg * 4 + r][d];
      acc[r][0].x += a * w0.x; acc[r][0].y += a * w0.y;
      acc[r][0].z += a * w0.z; acc[r][0].w += a * w0.w;
      acc[r][1].x += a * w1.x; acc[r][1].y += a * w1.y;
      acc[r][1].z += a * w1.z; acc[r][1].w += a * w1.w;
    }
  }

  float* obase = (cg < 32) ? (Hi + (size_t)(row0)*256 + cg * 8)
                           : (Hj + (size_t)(row0)*256 + (cg - 32) * 8);
#pragma unroll
  for (int r = 0; r < 4; ++r) {
    *(float4*)(obase + (size_t)(rg * 4 + r) * 256) = acc[r][0];
    *(float4*)(obase + (size_t)(rg * 4 + r) * 256 + 4) = acc[r][1];
  }
}

// ---------------------------------------------------------------------------
// Kernel B: one block per (b,i); processes all 32 j's.
//  Phase A: sA[j][k] = gelu(Hi[b,i][k] + Hj[b,j][k] + b1[k])   (exact erf gelu)
//  Phase G: e[j][c]  = sA[j][:] @ W2[:,c] + b2[c]   (fp32 register-tiled GEMM)
//  Phase L: logits[j][n] = (e[j][:] . cb[n][:]) * 10
//  Phase S: softmax over n (16)
//  Phase M: m[j][c] = sum_n alpha[j][n] * cb[n][c]
// ---------------------------------------------------------------------------
#define GSTEP(comp, wv)                                                        \
  acc0.x += a0.comp * wv.x; acc0.y += a0.comp * wv.y;                          \
  acc0.z += a0.comp * wv.z; acc0.w += a0.comp * wv.w;                          \
  acc1.x += a1.comp * wv.x; acc1.y += a1.comp * wv.y;                          \
  acc1.z += a1.comp * wv.z; acc1.w += a1.comp * wv.w;                          \
  acc2.x += a2.comp * wv.x; acc2.y += a2.comp * wv.y;                          \
  acc2.z += a2.comp * wv.z; acc2.w += a2.comp * wv.w;                          \
  acc3.x += a3.comp * wv.x; acc3.y += a3.comp * wv.y;                          \
  acc3.z += a3.comp * wv.z; acc3.w += a3.comp * wv.w;

__global__ __launch_bounds__(256, 2) void pair_kernel(
    const float* __restrict__ Hi, const float* __restrict__ Hj,
    const float* __restrict__ b1, const float* __restrict__ W2,
    const float* __restrict__ b2, const float* __restrict__ cb,
    float* __restrict__ out) {
  __shared__ float sA[32][256];   // 32 KB  gelu(h)
  __shared__ float sW[32][128];   // 16 KB  W2 k-chunk
  __shared__ float sCB[16][132];  // 8.25 KB codebook (padded: kills 8-way conflicts)
  __shared__ float sE[32][132];   // 16.5 KB e tile   (padded)
  __shared__ float sL[32][17];    // logits (padded)
  __shared__ float sAl[32][16];   // alpha

  const int tid = threadIdx.x;
  const int blk = blockIdx.x;  // = b*K + i
  const int b = blk >> 5;

  // stage codebook (2048 floats)
#pragma unroll
  for (int s = 0; s < 8; ++s) {
    int idx = tid + s * 256;
    sCB[idx >> 7][idx & 127] = cb[idx];
  }

  // ---- Phase A: gelu(h). thread owns column k = tid across all 32 pairs ----
  {
    const float hib = Hi[(size_t)blk * 256 + tid] + b1[tid];
    const float* hjp = Hj + (size_t)b * KK * 256 + tid;
#pragma unroll 4
    for (int p = 0; p < 32; ++p) {
      float x = hib + hjp[(size_t)p * 256];
      float g = 0.5f * x * (1.0f + erff(x * 0.70710678118654752f));
      sA[p][tid] = g;
    }
  }
  __syncthreads();

  // ---- Phase G: e = A @ W2, 32x128, K=256 in 8 chunks of 32 ----
  const int pg = tid >> 5;  // 0..7  -> pairs pg*4..+3
  const int cg = tid & 31;  // 0..31 -> cols  cg*4..+3
  float4 acc0 = make_float4(0.f, 0.f, 0.f, 0.f);
  float4 acc1 = acc0, acc2 = acc0, acc3 = acc0;

  for (int kc = 0; kc < 8; ++kc) {
    __syncthreads();  // previous sW fully consumed
#pragma unroll
    for (int s = 0; s < 4; ++s) {
      int idx = tid + s * 256;        // float4 units, 0..1023
      int r = idx >> 5, c4 = idx & 31;
      *(float4*)&sW[r][c4 * 4] =
          *(const float4*)(W2 + (size_t)(kc * 32 + r) * 128 + c4 * 4);
    }
    __syncthreads();

#pragma unroll
    for (int kk = 0; kk < 32; kk += 4) {
      const int k0 = kc * 32 + kk;
      float4 a0 = *(const float4*)&sA[pg * 4 + 0][k0];
      float4 a1 = *(const float4*)&sA[pg * 4 + 1][k0];
      float4 a2 = *(const float4*)&sA[pg * 4 + 2][k0];
      float4 a3 = *(const float4*)&sA[pg * 4 + 3][k0];
      float4 w0 = *(const float4*)&sW[kk + 0][cg * 4];
      float4 w1 = *(const float4*)&sW[kk + 1][cg * 4];
      float4 w2v = *(const float4*)&sW[kk + 2][cg * 4];
      float4 w3 = *(const float4*)&sW[kk + 3][cg * 4];
      GSTEP(x, w0)
      GSTEP(y, w1)
      GSTEP(z, w2v)
      GSTEP(w, w3)
    }
  }

  // add b2, write e to LDS + global (contiguous 16 KB per block)
  {
    float4 b2v = *(const float4*)(b2 + cg * 4);
    float* eg = out + O2 + (size_t)blk * (KK * DD);
#define EMIT(ACC, P)                                                           \
  {                                                                            \
    int pp = pg * 4 + (P);                                                     \
    float4 v = make_float4(ACC.x + b2v.x, ACC.y + b2v.y, ACC.z + b2v.z,        \
                           ACC.w + b2v.w);                                     \
    *(float4*)&sE[pp][cg * 4] = v;                                             \
    *(float4*)(eg + (size_t)pp * 128 + cg * 4) = v;                            \
  }
    EMIT(acc0, 0) EMIT(acc1, 1) EMIT(acc2, 2) EMIT(acc3, 3)
#undef EMIT
  }
  __syncthreads();

  // ---- Phase L: logits = (e . cb) * 10 ----
  {
    const int p = tid >> 3;   // 0..31
    const int n0 = tid & 7;   // handles n0 and n0+8
    float d0 = 0.f, d1 = 0.f;
#pragma unroll 8
    for (int c = 0; c < 128; c += 4) {
      float4 ev = *(const float4*)&sE[p][c];
      float4 c0 = *(const float4*)&sCB[n0][c];
      float4 c1 = *(const float4*)&sCB[n0 + 8][c];
      d0 += ev.x * c0.x + ev.y * c0.y + ev.z * c0.z + ev.w * c0.w;
      d1 += ev.x * c1.x + ev.y * c1.y + ev.z * c1.z + ev.w * c1.w;
    }
    d0 *= 10.0f; d1 *= 10.0f;
    sL[p][n0] = d0;
    sL[p][n0 + 8] = d1;
    float* lg = out + O3 + (size_t)blk * (KK * NN);
    lg[p * 16 + n0] = d0;
    lg[p * 16 + n0 + 8] = d1;
  }
  __syncthreads();

  // ---- Phase S: softmax over n=16, one thread per pair ----
  if (tid < 32) {
    const int p = tid;
    float l[16];
    float mx = -1e30f;
#pragma unroll
    for (int n = 0; n < 16; ++n) { l[n] = sL[p][n]; mx = fmaxf(mx, l[n]); }
    float s = 0.f;
#pragma unroll
    for (int n = 0; n < 16; ++n) { l[n] = expf(l[n] - mx); s += l[n]; }
    float inv = 1.0f / s;
    float* ag = out + O1 + (size_t)blk * (KK * NN) + (size_t)p * 16;
#pragma unroll
    for (int n = 0; n < 16; ++n) {
      float a = l[n] * inv;
      sAl[p][n] = a;
      ag[n] = a;
    }
  }
  __syncthreads();

  // ---- Phase M: m = alpha @ cb ----
  {
    float4 mac0 = make_float4(0.f, 0.f, 0.f, 0.f);
    float4 mac1 = mac0, mac2 = mac0, mac3 = mac0;
#pragma unroll
    for (int n = 0; n < 16; ++n) {
      float4 cv = *(const float4*)&sCB[n][cg * 4];
      float q0 = sAl[pg * 4 + 0][n];
      float q1 = sAl[pg * 4 + 1][n];
      float q2 = sAl[pg * 4 + 2][n];
      float q3 = sAl[pg * 4 + 3][n];
      mac0.x += q0 * cv.x; mac0.y += q0 * cv.y; mac0.z += q0 * cv.z; mac0.w += q0 * cv.w;
      mac1.x += q1 * cv.x; mac1.y += q1 * cv.y; mac1.z += q1 * cv.z; mac1.w += q1 * cv.w;
      mac2.x += q2 * cv.x; mac2.y += q2 * cv.y; mac2.z += q2 * cv.z; mac2.w += q2 * cv.w;
      mac3.x += q3 * cv.x; mac3.y += q3 * cv.y; mac3.z += q3 * cv.z; mac3.w += q3 * cv.w;
    }
    float* mg = out + O0 + (size_t)blk * (KK * DD);
    *(float4*)(mg + (size_t)(pg * 4 + 0) * 128 + cg * 4) = mac0;
    *(float4*)(mg + (size_t)(pg * 4 + 1) * 128 + cg * 4) = mac1;
    *(float4*)(mg + (size_t)(pg * 4 + 2) * 128 + cg * 4) = mac2;
    *(float4*)(mg + (size_t)(pg * 4 + 3) * 128 + cg * 4) = mac3;
  }
}

extern "C" void kernel_launch(void* const* d_in, const int* in_sizes, int n_in,
                              void* d_out, int out_size, void* d_ws, size_t ws_size,
                              hipStream_t stream) {
  const float* z  = (const float*)d_in[0];   // (256,32,128)
  const float* W1 = (const float*)d_in[1];   // (256,256)
  const float* b1 = (const float*)d_in[2];   // (256,)
  const float* W2 = (const float*)d_in[3];   // (256,128)
  const float* b2 = (const float*)d_in[4];   // (128,)
  const float* cb = (const float*)d_in[5];   // (16,128)
  float* out = (float*)d_out;

  // workspace: Hi (8192*256) + Hj (8192*256) fp32 = 16.8 MB
  float* Hi = (float*)d_ws;
  float* Hj = Hi + (size_t)8192 * 256;

  hproj_kernel<<<512, 256, 0, stream>>>(z, W1, Hi, Hj);
  pair_kernel<<<BB * KK, 256, 0, stream>>>(Hi, Hj, b1, W2, b2, cb, out);
}

// Round 2
// 264.737 us; speedup vs baseline: 1.5860x; 1.5860x over previous
//
#include <hip/hip_runtime.h>
#include <hip/hip_bf16.h>
#include <math.h>

// Problem constants
#define BB 256
#define KK 32
#define DD 128
#define HH 256
#define NN 16
// d_out layout (fp32, concatenated in return order)
#define O0 ((size_t)0)
#define O1 ((size_t)33554432)
#define O2 ((size_t)37748736)
#define O3 ((size_t)71303168)

typedef float f32x4 __attribute__((ext_vector_type(4)));
typedef short s16x8 __attribute__((ext_vector_type(8)));

static __device__ __forceinline__ short f2bf(float x) {
  __hip_bfloat16 h = __float2bfloat16(x);
  return *reinterpret_cast<short*>(&h);
}
static __device__ __forceinline__ float bf2f(short s) {
  __hip_bfloat16 h;
  *reinterpret_cast<short*>(&h) = s;
  return __bfloat162float(h);
}

// ---------------------------------------------------------------------------
// Kernel A: Hi[bk][h] = sum_d z[bk][d] * W1[d][h]; Hj likewise with W1[128+d].
// fp32 register-tiled. (~7us, not the bottleneck)
// ---------------------------------------------------------------------------
__global__ __launch_bounds__(256) void hproj_kernel(
    const float* __restrict__ z, const float* __restrict__ W1,
    float* __restrict__ Hi, float* __restrict__ Hj) {
  __shared__ float sz[16][128];
  const int tid = threadIdx.x;
  const int row0 = blockIdx.x * 16;

#pragma unroll
  for (int s = 0; s < 8; ++s) {
    int idx = tid + s * 256;
    int r = idx >> 7, c = idx & 127;
    sz[r][c] = z[(size_t)(row0 + r) * 128 + c];
  }
  __syncthreads();

  const int rg = tid >> 6;
  const int cg = tid & 63;
  const float* wbase = (cg < 32) ? (W1 + cg * 8) : (W1 + 128 * 256 + (cg - 32) * 8);

  float4 acc[4][2];
#pragma unroll
  for (int r = 0; r < 4; ++r) {
    acc[r][0] = make_float4(0.f, 0.f, 0.f, 0.f);
    acc[r][1] = make_float4(0.f, 0.f, 0.f, 0.f);
  }

  for (int d = 0; d < 128; ++d) {
    float4 w0 = *(const float4*)(wbase + (size_t)d * 256);
    float4 w1 = *(const float4*)(wbase + (size_t)d * 256 + 4);
#pragma unroll
    for (int r = 0; r < 4; ++r) {
      float a = sz[rg * 4 + r][d];
      acc[r][0].x += a * w0.x; acc[r][0].y += a * w0.y;
      acc[r][0].z += a * w0.z; acc[r][0].w += a * w0.w;
      acc[r][1].x += a * w1.x; acc[r][1].y += a * w1.y;
      acc[r][1].z += a * w1.z; acc[r][1].w += a * w1.w;
    }
  }

  float* obase = (cg < 32) ? (Hi + (size_t)(row0)*256 + cg * 8)
                           : (Hj + (size_t)(row0)*256 + (cg - 32) * 8);
#pragma unroll
  for (int r = 0; r < 4; ++r) {
    *(float4*)(obase + (size_t)(rg * 4 + r) * 256) = acc[r][0];
    *(float4*)(obase + (size_t)(rg * 4 + r) * 256 + 4) = acc[r][1];
  }
}

// ---------------------------------------------------------------------------
// W2 prep: split into hi/lo bf16 and transpose to [col][k] so each lane's
// B-fragment (8 k-contiguous bf16 at fixed col) is one 16B load.
// ---------------------------------------------------------------------------
__global__ __launch_bounds__(256) void wprep_kernel(
    const float* __restrict__ W2, short* __restrict__ Wh, short* __restrict__ Wl) {
  int idx = blockIdx.x * 256 + threadIdx.x;  // 32768 total
  int c = idx & 127, k = idx >> 7;
  float w = W2[(size_t)k * 128 + c];
  short hb = f2bf(w);
  short lb = f2bf(w - bf2f(hb));
  Wh[(size_t)c * 256 + k] = hb;
  Wl[(size_t)c * 256 + k] = lb;
}

// ---------------------------------------------------------------------------
// Kernel B: one block (256 thr = 4 waves) per (b,i); all 32 j's.
//  Phase A: gelu(Hi[b,i]+Hj[b,j]+b1) -> split bf16 (hi,lo) in swizzled LDS
//  Phase G: e = A @ W2 via 3-pass split-bf16 MFMA (AhWh + AlWh + AhWl)
//  Phase L/S/M: logits, softmax, m  (fp32 VALU, small)
// ---------------------------------------------------------------------------
__global__ __launch_bounds__(256, 2) void pair_kernel(
    const float* __restrict__ Hi, const float* __restrict__ Hj,
    const float* __restrict__ b1, const short* __restrict__ Wh,
    const short* __restrict__ Wl, const float* __restrict__ b2,
    const float* __restrict__ cb, float* __restrict__ out) {
  __shared__ short sAh[32 * 256];   // 16 KB  hi split, XOR-swizzled
  __shared__ short sAl[32 * 256];   // 16 KB  lo split, XOR-swizzled
  __shared__ float sE[32 * 132];    // 16.9 KB e tile (padded)
  __shared__ float sCB[16 * 132];   // 8.45 KB codebook (padded)
  __shared__ float sL[32][17];
  __shared__ float sAlp[32][16];

  const int tid = threadIdx.x;
  const int blk = blockIdx.x;  // = b*K + i
  const int b = blk >> 5;

  // stage codebook (16x128) into padded LDS
#pragma unroll
  for (int s = 0; s < 8; ++s) {
    int idx = tid + s * 256;
    sCB[(idx >> 7) * 132 + (idx & 127)] = cb[idx];
  }

  // ---- Phase A: gelu + split-bf16 into swizzled LDS ----
  // thread owns cols k0,k0+1 for 16 pairs (rows pb..pb+15)
  {
    const int k0 = (tid & 127) * 2;
    const int pb = (tid >> 7) * 16;
    const float2 hiv = *(const float2*)(Hi + (size_t)blk * 256 + k0);
    const float2 b1v = *(const float2*)(b1 + k0);
    const float hx = hiv.x + b1v.x;
    const float hy = hiv.y + b1v.y;
    const float* hjp = Hj + ((size_t)b * KK + pb) * 256 + k0;
    unsigned* aH = (unsigned*)sAh;
    unsigned* aL = (unsigned*)sAl;
    const int cw = tid & 127;  // u32 column index within row (256 bf16 = 128 u32)
#pragma unroll 4
    for (int p = 0; p < 16; ++p) {
      const int row = pb + p;
      float2 hj = *(const float2*)(hjp + (size_t)p * 256);
      float x0 = hx + hj.x;
      float x1 = hy + hj.y;
      float g0 = 0.5f * x0 * (1.0f + erff(x0 * 0.70710678118654752f));
      float g1 = 0.5f * x1 * (1.0f + erff(x1 * 0.70710678118654752f));
      short h0 = f2bf(g0), h1 = f2bf(g1);
      short l0 = f2bf(g0 - bf2f(h0)), l1 = f2bf(g1 - bf2f(h1));
      // byte addr = row*512 + ((cw*4) ^ ((row&7)<<4)); as u32 index:
      const int wi = row * 128 + ((cw ^ ((row & 7) << 2)));
      aH[wi] = (unsigned)(unsigned short)h0 | ((unsigned)(unsigned short)h1 << 16);
      aL[wi] = (unsigned)(unsigned short)l0 | ((unsigned)(unsigned short)l1 << 16);
    }
  }
  __syncthreads();

  // ---- Phase G: 32x128 GEMM, K=256, split-bf16 MFMA ----
  const int lane = tid & 63;
  const int wv = tid >> 6;       // wave 0..3 owns cols nb..nb+31
  const int nb = wv * 32;
  const int l4 = lane >> 4;      // 0..3
  const int l15 = lane & 15;

  f32x4 acc[2][2];
#pragma unroll
  for (int mt = 0; mt < 2; ++mt)
#pragma unroll
    for (int nt = 0; nt < 2; ++nt)
      acc[mt][nt] = (f32x4){0.f, 0.f, 0.f, 0.f};

  const int sw = (l15 & 7) << 4;                // row swizzle (same for row and row+16)
  const char* pAh = (const char*)sAh;
  const char* pAl = (const char*)sAl;
  const size_t gB0 = (size_t)(nb + l15) * 256 + l4 * 8;

#pragma unroll
  for (int ks = 0; ks < 8; ++ks) {
    const int cbyte = ks * 64 + l4 * 16;
    const int o0 = l15 * 512 + (cbyte ^ sw);
    const int o1 = (16 + l15) * 512 + (cbyte ^ sw);
    s16x8 ah0 = *(const s16x8*)(pAh + o0);
    s16x8 ah1 = *(const s16x8*)(pAh + o1);
    s16x8 al0 = *(const s16x8*)(pAl + o0);
    s16x8 al1 = *(const s16x8*)(pAl + o1);
    const size_t g0 = gB0 + ks * 32;
    const size_t g1 = g0 + 16 * 256;
    s16x8 bh0 = *(const s16x8*)(Wh + g0);
    s16x8 bh1 = *(const s16x8*)(Wh + g1);
    s16x8 bl0 = *(const s16x8*)(Wl + g0);
    s16x8 bl1 = *(const s16x8*)(Wl + g1);

    acc[0][0] = __builtin_amdgcn_mfma_f32_16x16x32_bf16(ah0, bh0, acc[0][0], 0, 0, 0);
    acc[0][0] = __builtin_amdgcn_mfma_f32_16x16x32_bf16(al0, bh0, acc[0][0], 0, 0, 0);
    acc[0][0] = __builtin_amdgcn_mfma_f32_16x16x32_bf16(ah0, bl0, acc[0][0], 0, 0, 0);
    acc[0][1] = __builtin_amdgcn_mfma_f32_16x16x32_bf16(ah0, bh1, acc[0][1], 0, 0, 0);
    acc[0][1] = __builtin_amdgcn_mfma_f32_16x16x32_bf16(al0, bh1, acc[0][1], 0, 0, 0);
    acc[0][1] = __builtin_amdgcn_mfma_f32_16x16x32_bf16(ah0, bl1, acc[0][1], 0, 0, 0);
    acc[1][0] = __builtin_amdgcn_mfma_f32_16x16x32_bf16(ah1, bh0, acc[1][0], 0, 0, 0);
    acc[1][0] = __builtin_amdgcn_mfma_f32_16x16x32_bf16(al1, bh0, acc[1][0], 0, 0, 0);
    acc[1][0] = __builtin_amdgcn_mfma_f32_16x16x32_bf16(ah1, bl0, acc[1][0], 0, 0, 0);
    acc[1][1] = __builtin_amdgcn_mfma_f32_16x16x32_bf16(ah1, bh1, acc[1][1], 0, 0, 0);
    acc[1][1] = __builtin_amdgcn_mfma_f32_16x16x32_bf16(al1, bh1, acc[1][1], 0, 0, 0);
    acc[1][1] = __builtin_amdgcn_mfma_f32_16x16x32_bf16(ah1, bl1, acc[1][1], 0, 0, 0);
  }

  // epilogue: +b2, store to sE (C/D layout: col = lane&15, row = (lane>>4)*4+r)
  {
    const float b2v0 = b2[nb + l15];
    const float b2v1 = b2[nb + 16 + l15];
#pragma unroll
    for (int mt = 0; mt < 2; ++mt) {
#pragma unroll
      for (int r = 0; r < 4; ++r) {
        const int row = mt * 16 + l4 * 4 + r;
        sE[row * 132 + nb + l15] = acc[mt][0][r] + b2v0;
        sE[row * 132 + nb + 16 + l15] = acc[mt][1][r] + b2v1;
      }
    }
  }
  __syncthreads();

  // ---- coalesced e write (4 float4 per thread) ----
  {
    float* eg = out + O2 + (size_t)blk * (KK * DD);
#pragma unroll
    for (int s = 0; s < 4; ++s) {
      int idx = tid + s * 256;       // float4 index, 0..1023
      int f = idx * 4;
      int p = f >> 7, c = f & 127;
      float4 v = *(const float4*)&sE[p * 132 + c];
      *(float4*)(eg + f) = v;
    }
  }

  // ---- Phase L: logits = (e . cb) * 10 ----
  {
    const int p = tid >> 3;
    const int n0 = tid & 7;
    float d0 = 0.f, d1 = 0.f;
#pragma unroll 8
    for (int c = 0; c < 128; c += 4) {
      float4 ev = *(const float4*)&sE[p * 132 + c];
      float4 c0 = *(const float4*)&sCB[n0 * 132 + c];
      float4 c1 = *(const float4*)&sCB[(n0 + 8) * 132 + c];
      d0 += ev.x * c0.x + ev.y * c0.y + ev.z * c0.z + ev.w * c0.w;
      d1 += ev.x * c1.x + ev.y * c1.y + ev.z * c1.z + ev.w * c1.w;
    }
    d0 *= 10.0f; d1 *= 10.0f;
    sL[p][n0] = d0;
    sL[p][n0 + 8] = d1;
    float* lg = out + O3 + (size_t)blk * (KK * NN);
    lg[p * 16 + n0] = d0;
    lg[p * 16 + n0 + 8] = d1;
  }
  __syncthreads();

  // ---- Phase S: softmax over n=16 ----
  if (tid < 32) {
    const int p = tid;
    float l[16];
    float mx = -1e30f;
#pragma unroll
    for (int n = 0; n < 16; ++n) { l[n] = sL[p][n]; mx = fmaxf(mx, l[n]); }
    float s = 0.f;
#pragma unroll
    for (int n = 0; n < 16; ++n) { l[n] = expf(l[n] - mx); s += l[n]; }
    float inv = 1.0f / s;
    float* ag = out + O1 + (size_t)blk * (KK * NN) + (size_t)p * 16;
#pragma unroll
    for (int n = 0; n < 16; ++n) {
      float a = l[n] * inv;
      sAlp[p][n] = a;
      ag[n] = a;
    }
  }
  __syncthreads();

  // ---- Phase M: m = alpha @ cb ----
  {
    const int pg = tid >> 5;
    const int cg = tid & 31;
    float4 mac0 = make_float4(0.f, 0.f, 0.f, 0.f);
    float4 mac1 = mac0, mac2 = mac0, mac3 = mac0;
#pragma unroll
    for (int n = 0; n < 16; ++n) {
      float4 cv = *(const float4*)&sCB[n * 132 + cg * 4];
      float q0 = sAlp[pg * 4 + 0][n];
      float q1 = sAlp[pg * 4 + 1][n];
      float q2 = sAlp[pg * 4 + 2][n];
      float q3 = sAlp[pg * 4 + 3][n];
      mac0.x += q0 * cv.x; mac0.y += q0 * cv.y; mac0.z += q0 * cv.z; mac0.w += q0 * cv.w;
      mac1.x += q1 * cv.x; mac1.y += q1 * cv.y; mac1.z += q1 * cv.z; mac1.w += q1 * cv.w;
      mac2.x += q2 * cv.x; mac2.y += q2 * cv.y; mac2.z += q2 * cv.z; mac2.w += q2 * cv.w;
      mac3.x += q3 * cv.x; mac3.y += q3 * cv.y; mac3.z += q3 * cv.z; mac3.w += q3 * cv.w;
    }
    float* mg = out + O0 + (size_t)blk * (KK * DD);
    *(float4*)(mg + (size_t)(pg * 4 + 0) * 128 + cg * 4) = mac0;
    *(float4*)(mg + (size_t)(pg * 4 + 1) * 128 + cg * 4) = mac1;
    *(float4*)(mg + (size_t)(pg * 4 + 2) * 128 + cg * 4) = mac2;
    *(float4*)(mg + (size_t)(pg * 4 + 3) * 128 + cg * 4) = mac3;
  }
}

extern "C" void kernel_launch(void* const* d_in, const int* in_sizes, int n_in,
                              void* d_out, int out_size, void* d_ws, size_t ws_size,
                              hipStream_t stream) {
  const float* z  = (const float*)d_in[0];   // (256,32,128)
  const float* W1 = (const float*)d_in[1];   // (256,256)
  const float* b1 = (const float*)d_in[2];   // (256,)
  const float* W2 = (const float*)d_in[3];   // (256,128)
  const float* b2 = (const float*)d_in[4];   // (128,)
  const float* cb = (const float*)d_in[5];   // (16,128)
  float* out = (float*)d_out;

  // ws layout: Hi (8M floats) | Hj (8M floats) | Wh (32K bf16) | Wl (32K bf16)
  float* Hi = (float*)d_ws;
  float* Hj = Hi + (size_t)8192 * 256;
  short* Wh = (short*)(Hj + (size_t)8192 * 256);
  short* Wl = Wh + (size_t)128 * 256;

  hproj_kernel<<<512, 256, 0, stream>>>(z, W1, Hi, Hj);
  wprep_kernel<<<128, 256, 0, stream>>>(W2, Wh, Wl);
  pair_kernel<<<BB * KK, 256, 0, stream>>>(Hi, Hj, b1, Wh, Wl, b2, cb, out);
}

// Round 3
// 240.666 us; speedup vs baseline: 1.7447x; 1.1000x over previous
//
#include <hip/hip_runtime.h>
#include <hip/hip_bf16.h>
#include <math.h>

// Problem constants
#define BB 256
#define KK 32
#define DD 128
#define HH 256
#define NN 16
// d_out layout (fp32, concatenated in return order)
#define O0 ((size_t)0)
#define O1 ((size_t)33554432)
#define O2 ((size_t)37748736)
#define O3 ((size_t)71303168)

typedef float f32x4 __attribute__((ext_vector_type(4)));
typedef short s16x8 __attribute__((ext_vector_type(8)));

static __device__ __forceinline__ short f2bf(float x) {
  __hip_bfloat16 h = __float2bfloat16(x);
  return *reinterpret_cast<short*>(&h);
}
static __device__ __forceinline__ float bf2f(short s) {
  __hip_bfloat16 h;
  *reinterpret_cast<short*>(&h) = s;
  return __bfloat162float(h);
}

// ---------------------------------------------------------------------------
// Kernel A: Hi[bk][h] = sum_d z[bk][d] * W1[d][h]; Hj likewise with W1[128+d].
// ---------------------------------------------------------------------------
__global__ __launch_bounds__(256) void hproj_kernel(
    const float* __restrict__ z, const float* __restrict__ W1,
    float* __restrict__ Hi, float* __restrict__ Hj) {
  __shared__ float sz[16][128];
  const int tid = threadIdx.x;
  const int row0 = blockIdx.x * 16;

#pragma unroll
  for (int s = 0; s < 8; ++s) {
    int idx = tid + s * 256;
    int r = idx >> 7, c = idx & 127;
    sz[r][c] = z[(size_t)(row0 + r) * 128 + c];
  }
  __syncthreads();

  const int rg = tid >> 6;
  const int cg = tid & 63;
  const float* wbase = (cg < 32) ? (W1 + cg * 8) : (W1 + 128 * 256 + (cg - 32) * 8);

  float4 acc[4][2];
#pragma unroll
  for (int r = 0; r < 4; ++r) {
    acc[r][0] = make_float4(0.f, 0.f, 0.f, 0.f);
    acc[r][1] = make_float4(0.f, 0.f, 0.f, 0.f);
  }

  for (int d = 0; d < 128; ++d) {
    float4 w0 = *(const float4*)(wbase + (size_t)d * 256);
    float4 w1 = *(const float4*)(wbase + (size_t)d * 256 + 4);
#pragma unroll
    for (int r = 0; r < 4; ++r) {
      float a = sz[rg * 4 + r][d];
      acc[r][0].x += a * w0.x; acc[r][0].y += a * w0.y;
      acc[r][0].z += a * w0.z; acc[r][0].w += a * w0.w;
      acc[r][1].x += a * w1.x; acc[r][1].y += a * w1.y;
      acc[r][1].z += a * w1.z; acc[r][1].w += a * w1.w;
    }
  }

  float* obase = (cg < 32) ? (Hi + (size_t)(row0)*256 + cg * 8)
                           : (Hj + (size_t)(row0)*256 + (cg - 32) * 8);
#pragma unroll
  for (int r = 0; r < 4; ++r) {
    *(float4*)(obase + (size_t)(rg * 4 + r) * 256) = acc[r][0];
    *(float4*)(obase + (size_t)(rg * 4 + r) * 256 + 4) = acc[r][1];
  }
}

// ---------------------------------------------------------------------------
// Prep: W2 -> hi/lo bf16 transposed [col][k]; cb -> hi/lo bf16 [n][k].
// ---------------------------------------------------------------------------
__global__ __launch_bounds__(256) void wprep_kernel(
    const float* __restrict__ W2, const float* __restrict__ cb,
    short* __restrict__ Wh, short* __restrict__ Wl,
    short* __restrict__ cbh, short* __restrict__ cbl) {
  int idx = blockIdx.x * 256 + threadIdx.x;  // 32768 total
  int c = idx & 127, k = idx >> 7;
  float w = W2[(size_t)k * 128 + c];
  short hb = f2bf(w);
  short lb = f2bf(w - bf2f(hb));
  Wh[(size_t)c * 256 + k] = hb;
  Wl[(size_t)c * 256 + k] = lb;
  if (idx < 2048) {                          // cb is (16,128) = [n][k] already
    float v = cb[idx];
    short h = f2bf(v);
    cbh[idx] = h;
    cbl[idx] = f2bf(v - bf2f(h));
  }
}

// ---------------------------------------------------------------------------
// Kernel B: one block (4 waves) per (b,i).
//  A: gelu(Hi+Hj+b1) -> split bf16 in swizzled LDS (sAh, u.Al)
//  G: e = A @ W2   (3-pass split-bf16 MFMA, wave owns 32 cols)
//  E: e -> global (fp32, from regs) + split bf16 -> swizzled LDS (u.e)
//  L: logits = e @ cbT * 10 (MFMA, waves 0-1), softmax in-register (shfl)
//  M: m = alpha @ cb (VALU)
// ---------------------------------------------------------------------------
__global__ __launch_bounds__(256, 3) void pair_kernel(
    const float* __restrict__ Hi, const float* __restrict__ Hj,
    const float* __restrict__ b1, const short* __restrict__ Wh,
    const short* __restrict__ Wl, const float* __restrict__ b2,
    const float* __restrict__ cb, const short* __restrict__ cbh,
    const short* __restrict__ cbl, float* __restrict__ out) {
  __shared__ short sAh[32 * 256];   // 16 KB  gelu hi split, XOR-swizzled
  __shared__ union {
    short Al[32 * 256];             // 16 KB  gelu lo split (dead after G)
    struct { short Eh[32 * 128]; short El[32 * 128]; } e;  // e splits, swizzled
  } u;
  __shared__ float sCB[16 * 132];   // 8.45 KB codebook fp32 (padded)
  __shared__ float sAlp[32][16];    // 2 KB alpha

  const int tid = threadIdx.x;
  const int blk = blockIdx.x;  // = b*K + i
  const int b = blk >> 5;

  // stage codebook fp32 (for phase M)
#pragma unroll
  for (int s = 0; s < 8; ++s) {
    int idx = tid + s * 256;
    sCB[(idx >> 7) * 132 + (idx & 127)] = cb[idx];
  }

  // ---- Phase A: gelu + split-bf16 into swizzled LDS ----
  {
    const int k0 = (tid & 127) * 2;
    const int pb = (tid >> 7) * 16;
    const float2 hiv = *(const float2*)(Hi + (size_t)blk * 256 + k0);
    const float2 b1v = *(const float2*)(b1 + k0);
    const float hx = hiv.x + b1v.x;
    const float hy = hiv.y + b1v.y;
    const float* hjp = Hj + ((size_t)b * KK + pb) * 256 + k0;
    unsigned* aH = (unsigned*)sAh;
    unsigned* aL = (unsigned*)u.Al;
    const int cw = tid & 127;
#pragma unroll 4
    for (int p = 0; p < 16; ++p) {
      const int row = pb + p;
      float2 hj = *(const float2*)(hjp + (size_t)p * 256);
      float x0 = hx + hj.x;
      float x1 = hy + hj.y;
      float g0 = 0.5f * x0 * (1.0f + erff(x0 * 0.70710678118654752f));
      float g1 = 0.5f * x1 * (1.0f + erff(x1 * 0.70710678118654752f));
      short h0 = f2bf(g0), h1 = f2bf(g1);
      short l0 = f2bf(g0 - bf2f(h0)), l1 = f2bf(g1 - bf2f(h1));
      const int wi = row * 128 + ((cw ^ ((row & 7) << 2)));
      aH[wi] = (unsigned)(unsigned short)h0 | ((unsigned)(unsigned short)h1 << 16);
      aL[wi] = (unsigned)(unsigned short)l0 | ((unsigned)(unsigned short)l1 << 16);
    }
  }
  __syncthreads();

  // ---- Phase G: 32x128 GEMM, K=256, split-bf16 MFMA ----
  const int lane = tid & 63;
  const int wv = tid >> 6;       // wave owns cols nb..nb+31
  const int nb = wv * 32;
  const int l4 = lane >> 4;
  const int l15 = lane & 15;

  f32x4 acc[2][2];
#pragma unroll
  for (int mt = 0; mt < 2; ++mt)
#pragma unroll
    for (int nt = 0; nt < 2; ++nt)
      acc[mt][nt] = (f32x4){0.f, 0.f, 0.f, 0.f};

  const int sw = (l15 & 7) << 4;
  const char* pAh = (const char*)sAh;
  const char* pAl = (const char*)u.Al;
  const size_t gB0 = (size_t)(nb + l15) * 256 + l4 * 8;

#pragma unroll
  for (int ks = 0; ks < 8; ++ks) {
    const int cbyte = ks * 64 + l4 * 16;
    const int o0 = l15 * 512 + (cbyte ^ sw);
    const int o1 = (16 + l15) * 512 + (cbyte ^ sw);
    s16x8 ah0 = *(const s16x8*)(pAh + o0);
    s16x8 ah1 = *(const s16x8*)(pAh + o1);
    s16x8 al0 = *(const s16x8*)(pAl + o0);
    s16x8 al1 = *(const s16x8*)(pAl + o1);
    const size_t g0 = gB0 + ks * 32;
    const size_t g1 = g0 + 16 * 256;
    s16x8 bh0 = *(const s16x8*)(Wh + g0);
    s16x8 bh1 = *(const s16x8*)(Wh + g1);
    s16x8 bl0 = *(const s16x8*)(Wl + g0);
    s16x8 bl1 = *(const s16x8*)(Wl + g1);

    acc[0][0] = __builtin_amdgcn_mfma_f32_16x16x32_bf16(ah0, bh0, acc[0][0], 0, 0, 0);
    acc[0][0] = __builtin_amdgcn_mfma_f32_16x16x32_bf16(al0, bh0, acc[0][0], 0, 0, 0);
    acc[0][0] = __builtin_amdgcn_mfma_f32_16x16x32_bf16(ah0, bl0, acc[0][0], 0, 0, 0);
    acc[0][1] = __builtin_amdgcn_mfma_f32_16x16x32_bf16(ah0, bh1, acc[0][1], 0, 0, 0);
    acc[0][1] = __builtin_amdgcn_mfma_f32_16x16x32_bf16(al0, bh1, acc[0][1], 0, 0, 0);
    acc[0][1] = __builtin_amdgcn_mfma_f32_16x16x32_bf16(ah0, bl1, acc[0][1], 0, 0, 0);
    acc[1][0] = __builtin_amdgcn_mfma_f32_16x16x32_bf16(ah1, bh0, acc[1][0], 0, 0, 0);
    acc[1][0] = __builtin_amdgcn_mfma_f32_16x16x32_bf16(al1, bh0, acc[1][0], 0, 0, 0);
    acc[1][0] = __builtin_amdgcn_mfma_f32_16x16x32_bf16(ah1, bl0, acc[1][0], 0, 0, 0);
    acc[1][1] = __builtin_amdgcn_mfma_f32_16x16x32_bf16(ah1, bh1, acc[1][1], 0, 0, 0);
    acc[1][1] = __builtin_amdgcn_mfma_f32_16x16x32_bf16(al1, bh1, acc[1][1], 0, 0, 0);
    acc[1][1] = __builtin_amdgcn_mfma_f32_16x16x32_bf16(ah1, bl1, acc[1][1], 0, 0, 0);
  }

  __syncthreads();  // all waves done reading sAh/u.Al; u.e may now be written

  // ---- Phase E: +b2, write fp32 e to global from regs, split bf16 to LDS ----
  {
    const float b2v0 = b2[nb + l15];
    const float b2v1 = b2[nb + 16 + l15];
    float* eg = out + O2 + (size_t)blk * (KK * DD);
    char* pEh = (char*)u.e.Eh;
    char* pEl = (char*)u.e.El;
#pragma unroll
    for (int mt = 0; mt < 2; ++mt) {
#pragma unroll
      for (int r = 0; r < 4; ++r) {
        const int row = mt * 16 + l4 * 4 + r;
        const int rsw = (row & 7) << 4;
        const float e0 = acc[mt][0][r] + b2v0;
        const float e1 = acc[mt][1][r] + b2v1;
        eg[row * 128 + nb + l15] = e0;
        eg[row * 128 + nb + 16 + l15] = e1;
        short h0 = f2bf(e0), h1 = f2bf(e1);
        short lo0 = f2bf(e0 - bf2f(h0)), lo1 = f2bf(e1 - bf2f(h1));
        const int i0 = row * 256 + (((nb + l15) * 2) ^ rsw);
        const int i1 = row * 256 + (((nb + 16 + l15) * 2) ^ rsw);
        *(short*)(pEh + i0) = h0;
        *(short*)(pEh + i1) = h1;
        *(short*)(pEl + i0) = lo0;
        *(short*)(pEl + i1) = lo1;
      }
    }
  }
  __syncthreads();

  // ---- Phase L: logits via MFMA (waves 0,1), softmax in-register ----
  if (wv < 2) {
    const int mrow = wv * 16;
    f32x4 lacc = (f32x4){0.f, 0.f, 0.f, 0.f};
    const char* pEh = (const char*)u.e.Eh;
    const char* pEl = (const char*)u.e.El;
    const int rowa = mrow + l15;
    const int rsw = (rowa & 7) << 4;
#pragma unroll
    for (int ks = 0; ks < 4; ++ks) {
      const int cbyte = ks * 64 + l4 * 16;
      const int o = rowa * 256 + (cbyte ^ rsw);
      s16x8 eh = *(const s16x8*)(pEh + o);
      s16x8 el = *(const s16x8*)(pEl + o);
      const size_t g = (size_t)l15 * 128 + ks * 32 + l4 * 8;
      s16x8 ch = *(const s16x8*)(cbh + g);
      s16x8 cl = *(const s16x8*)(cbl + g);
      lacc = __builtin_amdgcn_mfma_f32_16x16x32_bf16(eh, ch, lacc, 0, 0, 0);
      lacc = __builtin_amdgcn_mfma_f32_16x16x32_bf16(el, ch, lacc, 0, 0, 0);
      lacc = __builtin_amdgcn_mfma_f32_16x16x32_bf16(eh, cl, lacc, 0, 0, 0);
    }
    // C layout: col n = l15, row = mrow + l4*4 + r
    float* lg_out = out + O3 + (size_t)blk * (KK * NN);
    float* ag_out = out + O1 + (size_t)blk * (KK * NN);
#pragma unroll
    for (int r = 0; r < 4; ++r) {
      const int row = mrow + l4 * 4 + r;
      float lg = lacc[r] * 10.0f;
      float mx = lg;
#pragma unroll
      for (int m = 1; m < 16; m <<= 1) mx = fmaxf(mx, __shfl_xor(mx, m));
      float p = __expf(lg - mx);
      float s = p;
#pragma unroll
      for (int m = 1; m < 16; m <<= 1) s += __shfl_xor(s, m);
      float a = p / s;
      lg_out[row * 16 + l15] = lg;
      ag_out[row * 16 + l15] = a;
      sAlp[row][l15] = a;
    }
  }
  __syncthreads();

  // ---- Phase M: m = alpha @ cb (VALU) ----
  {
    const int pg = tid >> 5;
    const int cg = tid & 31;
    float4 mac0 = make_float4(0.f, 0.f, 0.f, 0.f);
    float4 mac1 = mac0, mac2 = mac0, mac3 = mac0;
#pragma unroll
    for (int n4 = 0; n4 < 4; ++n4) {
      float4 q0 = *(const float4*)&sAlp[pg * 4 + 0][n4 * 4];
      float4 q1 = *(const float4*)&sAlp[pg * 4 + 1][n4 * 4];
      float4 q2 = *(const float4*)&sAlp[pg * 4 + 2][n4 * 4];
      float4 q3 = *(const float4*)&sAlp[pg * 4 + 3][n4 * 4];
#pragma unroll
      for (int nn = 0; nn < 4; ++nn) {
        const int n = n4 * 4 + nn;
        float4 cv = *(const float4*)&sCB[n * 132 + cg * 4];
        float a0 = (nn == 0) ? q0.x : (nn == 1) ? q0.y : (nn == 2) ? q0.z : q0.w;
        float a1 = (nn == 0) ? q1.x : (nn == 1) ? q1.y : (nn == 2) ? q1.z : q1.w;
        float a2 = (nn == 0) ? q2.x : (nn == 1) ? q2.y : (nn == 2) ? q2.z : q2.w;
        float a3 = (nn == 0) ? q3.x : (nn == 1) ? q3.y : (nn == 2) ? q3.z : q3.w;
        mac0.x += a0 * cv.x; mac0.y += a0 * cv.y; mac0.z += a0 * cv.z; mac0.w += a0 * cv.w;
        mac1.x += a1 * cv.x; mac1.y += a1 * cv.y; mac1.z += a1 * cv.z; mac1.w += a1 * cv.w;
        mac2.x += a2 * cv.x; mac2.y += a2 * cv.y; mac2.z += a2 * cv.z; mac2.w += a2 * cv.w;
        mac3.x += a3 * cv.x; mac3.y += a3 * cv.y; mac3.z += a3 * cv.z; mac3.w += a3 * cv.w;
      }
    }
    float* mg = out + O0 + (size_t)blk * (KK * DD);
    *(float4*)(mg + (size_t)(pg * 4 + 0) * 128 + cg * 4) = mac0;
    *(float4*)(mg + (size_t)(pg * 4 + 1) * 128 + cg * 4) = mac1;
    *(float4*)(mg + (size_t)(pg * 4 + 2) * 128 + cg * 4) = mac2;
    *(float4*)(mg + (size_t)(pg * 4 + 3) * 128 + cg * 4) = mac3;
  }
}

extern "C" void kernel_launch(void* const* d_in, const int* in_sizes, int n_in,
                              void* d_out, int out_size, void* d_ws, size_t ws_size,
                              hipStream_t stream) {
  const float* z  = (const float*)d_in[0];   // (256,32,128)
  const float* W1 = (const float*)d_in[1];   // (256,256)
  const float* b1 = (const float*)d_in[2];   // (256,)
  const float* W2 = (const float*)d_in[3];   // (256,128)
  const float* b2 = (const float*)d_in[4];   // (128,)
  const float* cb = (const float*)d_in[5];   // (16,128)
  float* out = (float*)d_out;

  // ws: Hi | Hj (fp32 8192x256 each) | Wh | Wl (32K s16) | cbh | cbl (2K s16)
  float* Hi = (float*)d_ws;
  float* Hj = Hi + (size_t)8192 * 256;
  short* Wh = (short*)(Hj + (size_t)8192 * 256);
  short* Wl = Wh + (size_t)128 * 256;
  short* cbh = Wl + (size_t)128 * 256;
  short* cbl = cbh + (size_t)2048;

  hproj_kernel<<<512, 256, 0, stream>>>(z, W1, Hi, Hj);
  wprep_kernel<<<128, 256, 0, stream>>>(W2, cb, Wh, Wl, cbh, cbl);
  pair_kernel<<<BB * KK, 256, 0, stream>>>(Hi, Hj, b1, Wh, Wl, b2, cb, cbh, cbl, out);
}

// Round 4
// 209.269 us; speedup vs baseline: 2.0064x; 1.1500x over previous
//
#include <hip/hip_runtime.h>
#include <hip/hip_bf16.h>
#include <math.h>

// Problem constants
#define BB 256
#define KK 32
#define DD 128
#define HH 256
#define NN 16
// d_out layout (fp32, concatenated in return order)
#define O0 ((size_t)0)
#define O1 ((size_t)33554432)
#define O2 ((size_t)37748736)
#define O3 ((size_t)71303168)

typedef float f32x4 __attribute__((ext_vector_type(4)));
typedef short s16x8 __attribute__((ext_vector_type(8)));

static __device__ __forceinline__ short f2bf(float x) {
  __hip_bfloat16 h = __float2bfloat16(x);
  return *reinterpret_cast<short*>(&h);
}
static __device__ __forceinline__ float bf2f(short s) {
  __hip_bfloat16 h;
  *reinterpret_cast<short*>(&h) = s;
  return __bfloat162float(h);
}

// exact-erf gelu via Abramowitz-Stegun 7.1.26 (|erf err| <= 1.5e-7)
static __device__ __forceinline__ float gelu_exact(float x) {
  float ax = fabsf(x) * 0.70710678118654752f;
  float t = __builtin_amdgcn_rcpf(fmaf(0.3275911f, ax, 1.0f));
  float p = fmaf(1.061405429f, t, -1.453152027f);
  p = fmaf(p, t, 1.421413741f);
  p = fmaf(p, t, -0.284496736f);
  p = fmaf(p, t, 0.254829592f);
  p *= t;
  float e = __expf(-ax * ax);
  float er = fmaf(-p, e, 1.0f);  // erf(|x|/sqrt2)
  er = copysignf(er, x);
  return 0.5f * x * (1.0f + er);
}

// ---------------------------------------------------------------------------
// Prep: z -> bf16; W1 -> transposed hi/lo bf16 [col 512][k 128]
//       (cols 0..255 = h_i part, 256..511 = h_j part);
//       W2 -> transposed hi/lo bf16 [col 128][k 256]; cb -> hi/lo [n][k].
// ---------------------------------------------------------------------------
__global__ __launch_bounds__(256) void prep_kernel(
    const float* __restrict__ z, const float* __restrict__ W1,
    const float* __restrict__ W2, const float* __restrict__ cb,
    short* __restrict__ zb, short* __restrict__ W1th, short* __restrict__ W1tl,
    short* __restrict__ Wh, short* __restrict__ Wl,
    short* __restrict__ cbh, short* __restrict__ cbl) {
  const int idx = blockIdx.x * 256 + threadIdx.x;  // 1,048,576 total
  zb[idx] = f2bf(z[idx]);
  if (idx < 512 * 128) {  // W1t
    int c = idx >> 7, k = idx & 127;
    float w = (c < 256) ? W1[(size_t)k * 256 + c]
                        : W1[(size_t)(128 + k) * 256 + (c - 256)];
    short h = f2bf(w);
    W1th[idx] = h;
    W1tl[idx] = f2bf(w - bf2f(h));
  }
  if (idx < 128 * 256) {  // W2t: [c][k]
    int c = idx >> 8, k = idx & 255;
    float w = W2[(size_t)k * 128 + c];
    short h = f2bf(w);
    Wh[idx] = h;
    Wl[idx] = f2bf(w - bf2f(h));
  }
  if (idx < 2048) {
    float v = cb[idx];
    short h = f2bf(v);
    cbh[idx] = h;
    cbl[idx] = f2bf(v - bf2f(h));
  }
}

// ---------------------------------------------------------------------------
// H projection via MFMA: Hcat[8192][512] = zb(8192x128) @ W1t^T (split-bf16,
// 2-pass: zb*(W1h+W1l)). Block = 32 rows x 128 cols (4 waves x 32 cols).
// ---------------------------------------------------------------------------
__global__ __launch_bounds__(256) void hproj_mfma(
    const short* __restrict__ zb, const short* __restrict__ W1th,
    const short* __restrict__ W1tl, float* __restrict__ H) {
  const int tid = threadIdx.x;
  const int lane = tid & 63;
  const int wv = tid >> 6;
  const int l4 = lane >> 4, l15 = lane & 15;
  const int row0 = blockIdx.x * 32;
  const int col0 = blockIdx.y * 128 + wv * 32;

  f32x4 acc[2][2];
#pragma unroll
  for (int mt = 0; mt < 2; ++mt)
#pragma unroll
    for (int nt = 0; nt < 2; ++nt)
      acc[mt][nt] = (f32x4){0.f, 0.f, 0.f, 0.f};

#pragma unroll
  for (int ks = 0; ks < 4; ++ks) {
    const int kof = ks * 32 + l4 * 8;
    s16x8 a0 = *(const s16x8*)(zb + (size_t)(row0 + l15) * 128 + kof);
    s16x8 a1 = *(const s16x8*)(zb + (size_t)(row0 + 16 + l15) * 128 + kof);
    s16x8 bh0 = *(const s16x8*)(W1th + (size_t)(col0 + l15) * 128 + kof);
    s16x8 bh1 = *(const s16x8*)(W1th + (size_t)(col0 + 16 + l15) * 128 + kof);
    s16x8 bl0 = *(const s16x8*)(W1tl + (size_t)(col0 + l15) * 128 + kof);
    s16x8 bl1 = *(const s16x8*)(W1tl + (size_t)(col0 + 16 + l15) * 128 + kof);
    acc[0][0] = __builtin_amdgcn_mfma_f32_16x16x32_bf16(a0, bh0, acc[0][0], 0, 0, 0);
    acc[0][0] = __builtin_amdgcn_mfma_f32_16x16x32_bf16(a0, bl0, acc[0][0], 0, 0, 0);
    acc[0][1] = __builtin_amdgcn_mfma_f32_16x16x32_bf16(a0, bh1, acc[0][1], 0, 0, 0);
    acc[0][1] = __builtin_amdgcn_mfma_f32_16x16x32_bf16(a0, bl1, acc[0][1], 0, 0, 0);
    acc[1][0] = __builtin_amdgcn_mfma_f32_16x16x32_bf16(a1, bh0, acc[1][0], 0, 0, 0);
    acc[1][0] = __builtin_amdgcn_mfma_f32_16x16x32_bf16(a1, bl0, acc[1][0], 0, 0, 0);
    acc[1][1] = __builtin_amdgcn_mfma_f32_16x16x32_bf16(a1, bh1, acc[1][1], 0, 0, 0);
    acc[1][1] = __builtin_amdgcn_mfma_f32_16x16x32_bf16(a1, bl1, acc[1][1], 0, 0, 0);
  }

#pragma unroll
  for (int mt = 0; mt < 2; ++mt)
#pragma unroll
    for (int nt = 0; nt < 2; ++nt)
#pragma unroll
      for (int r = 0; r < 4; ++r)
        H[(size_t)(row0 + mt * 16 + l4 * 4 + r) * 512 + col0 + nt * 16 + l15] =
            acc[mt][nt][r];
}

// ---------------------------------------------------------------------------
// Kernel B: one block (4 waves) per (b,i).
// ---------------------------------------------------------------------------
__global__ __launch_bounds__(256, 4) void pair_kernel(
    const float* __restrict__ Hcat, const float* __restrict__ b1,
    const short* __restrict__ Wh, const short* __restrict__ Wl,
    const float* __restrict__ b2, const float* __restrict__ cb,
    const short* __restrict__ cbh, const short* __restrict__ cbl,
    float* __restrict__ out) {
  __shared__ short sAh[32 * 256];  // 16 KB gelu hi split, XOR-swizzled
  __shared__ union {
    short Al[32 * 256];  // 16 KB gelu lo split (dead after G)
    struct { short Eh[32 * 128]; short El[32 * 128]; } e;
  } u;
  __shared__ float sAlp[32][16];  // 2 KB alpha

  const int tid = threadIdx.x;
  const int blk = blockIdx.x;  // = b*K + i
  const int b = blk >> 5;

  // ---- Phase A: gelu + split-bf16 into swizzled LDS ----
  {
    const int k0 = (tid & 127) * 2;
    const int pb = (tid >> 7) * 16;
    const float2 hiv = *(const float2*)(Hcat + (size_t)blk * 512 + k0);
    const float2 b1v = *(const float2*)(b1 + k0);
    const float hx = hiv.x + b1v.x;
    const float hy = hiv.y + b1v.y;
    const float* hjp = Hcat + ((size_t)b * KK + pb) * 512 + 256 + k0;
    unsigned* aH = (unsigned*)sAh;
    unsigned* aL = (unsigned*)u.Al;
    const int cw = tid & 127;
#pragma unroll 4
    for (int p = 0; p < 16; ++p) {
      const int row = pb + p;
      float2 hj = *(const float2*)(hjp + (size_t)p * 512);
      float g0 = gelu_exact(hx + hj.x);
      float g1 = gelu_exact(hy + hj.y);
      short h0 = f2bf(g0), h1 = f2bf(g1);
      short l0 = f2bf(g0 - bf2f(h0)), l1 = f2bf(g1 - bf2f(h1));
      const int wi = row * 128 + ((cw ^ ((row & 7) << 2)));
      aH[wi] = (unsigned)(unsigned short)h0 | ((unsigned)(unsigned short)h1 << 16);
      aL[wi] = (unsigned)(unsigned short)l0 | ((unsigned)(unsigned short)l1 << 16);
    }
  }
  __syncthreads();

  // ---- Phase G: 32x128 GEMM, K=256, split-bf16 MFMA ----
  const int lane = tid & 63;
  const int wv = tid >> 6;  // wave owns cols nb..nb+31
  const int nb = wv * 32;
  const int l4 = lane >> 4;
  const int l15 = lane & 15;

  f32x4 acc[2][2];
#pragma unroll
  for (int mt = 0; mt < 2; ++mt)
#pragma unroll
    for (int nt = 0; nt < 2; ++nt)
      acc[mt][nt] = (f32x4){0.f, 0.f, 0.f, 0.f};

  const int sw = (l15 & 7) << 4;
  const char* pAh = (const char*)sAh;
  const char* pAl = (const char*)u.Al;
  const size_t gB0 = (size_t)(nb + l15) * 256 + l4 * 8;

#pragma unroll
  for (int ks = 0; ks < 8; ++ks) {
    const int cbyte = ks * 64 + l4 * 16;
    const int o0 = l15 * 512 + (cbyte ^ sw);
    const int o1 = (16 + l15) * 512 + (cbyte ^ sw);
    s16x8 ah0 = *(const s16x8*)(pAh + o0);
    s16x8 ah1 = *(const s16x8*)(pAh + o1);
    s16x8 al0 = *(const s16x8*)(pAl + o0);
    s16x8 al1 = *(const s16x8*)(pAl + o1);
    const size_t g0 = gB0 + ks * 32;
    const size_t g1 = g0 + 16 * 256;
    s16x8 bh0 = *(const s16x8*)(Wh + g0);
    s16x8 bh1 = *(const s16x8*)(Wh + g1);
    s16x8 bl0 = *(const s16x8*)(Wl + g0);
    s16x8 bl1 = *(const s16x8*)(Wl + g1);

    acc[0][0] = __builtin_amdgcn_mfma_f32_16x16x32_bf16(ah0, bh0, acc[0][0], 0, 0, 0);
    acc[0][0] = __builtin_amdgcn_mfma_f32_16x16x32_bf16(al0, bh0, acc[0][0], 0, 0, 0);
    acc[0][0] = __builtin_amdgcn_mfma_f32_16x16x32_bf16(ah0, bl0, acc[0][0], 0, 0, 0);
    acc[0][1] = __builtin_amdgcn_mfma_f32_16x16x32_bf16(ah0, bh1, acc[0][1], 0, 0, 0);
    acc[0][1] = __builtin_amdgcn_mfma_f32_16x16x32_bf16(al0, bh1, acc[0][1], 0, 0, 0);
    acc[0][1] = __builtin_amdgcn_mfma_f32_16x16x32_bf16(ah0, bl1, acc[0][1], 0, 0, 0);
    acc[1][0] = __builtin_amdgcn_mfma_f32_16x16x32_bf16(ah1, bh0, acc[1][0], 0, 0, 0);
    acc[1][0] = __builtin_amdgcn_mfma_f32_16x16x32_bf16(al1, bh0, acc[1][0], 0, 0, 0);
    acc[1][0] = __builtin_amdgcn_mfma_f32_16x16x32_bf16(ah1, bl0, acc[1][0], 0, 0, 0);
    acc[1][1] = __builtin_amdgcn_mfma_f32_16x16x32_bf16(ah1, bh1, acc[1][1], 0, 0, 0);
    acc[1][1] = __builtin_amdgcn_mfma_f32_16x16x32_bf16(al1, bh1, acc[1][1], 0, 0, 0);
    acc[1][1] = __builtin_amdgcn_mfma_f32_16x16x32_bf16(ah1, bl1, acc[1][1], 0, 0, 0);
  }

  __syncthreads();  // sAh/u.Al fully consumed; u.e may be written

  // ---- Phase E: +b2, fp32 e to global from regs, bf16 splits to LDS ----
  {
    const float b2v0 = b2[nb + l15];
    const float b2v1 = b2[nb + 16 + l15];
    float* eg = out + O2 + (size_t)blk * (KK * DD);
    char* pEh = (char*)u.e.Eh;
    char* pEl = (char*)u.e.El;
#pragma unroll
    for (int mt = 0; mt < 2; ++mt) {
#pragma unroll
      for (int r = 0; r < 4; ++r) {
        const int row = mt * 16 + l4 * 4 + r;
        const int rsw = (row & 7) << 4;
        const float e0 = acc[mt][0][r] + b2v0;
        const float e1 = acc[mt][1][r] + b2v1;
        eg[row * 128 + nb + l15] = e0;
        eg[row * 128 + nb + 16 + l15] = e1;
        short h0 = f2bf(e0), h1 = f2bf(e1);
        short lo0 = f2bf(e0 - bf2f(h0)), lo1 = f2bf(e1 - bf2f(h1));
        const int i0 = row * 256 + (((nb + l15) * 2) ^ rsw);
        const int i1 = row * 256 + (((nb + 16 + l15) * 2) ^ rsw);
        *(short*)(pEh + i0) = h0;
        *(short*)(pEh + i1) = h1;
        *(short*)(pEl + i0) = lo0;
        *(short*)(pEl + i1) = lo1;
      }
    }
  }
  __syncthreads();

  // ---- Phase L: logits via MFMA (waves 0,1), softmax in-register ----
  if (wv < 2) {
    const int mrow = wv * 16;
    f32x4 lacc = (f32x4){0.f, 0.f, 0.f, 0.f};
    const char* pEh = (const char*)u.e.Eh;
    const char* pEl = (const char*)u.e.El;
    const int rowa = mrow + l15;
    const int rsw = (rowa & 7) << 4;
#pragma unroll
    for (int ks = 0; ks < 4; ++ks) {
      const int cbyte = ks * 64 + l4 * 16;
      const int o = rowa * 256 + (cbyte ^ rsw);
      s16x8 eh = *(const s16x8*)(pEh + o);
      s16x8 el = *(const s16x8*)(pEl + o);
      const size_t g = (size_t)l15 * 128 + ks * 32 + l4 * 8;
      s16x8 ch = *(const s16x8*)(cbh + g);
      s16x8 cl = *(const s16x8*)(cbl + g);
      lacc = __builtin_amdgcn_mfma_f32_16x16x32_bf16(eh, ch, lacc, 0, 0, 0);
      lacc = __builtin_amdgcn_mfma_f32_16x16x32_bf16(el, ch, lacc, 0, 0, 0);
      lacc = __builtin_amdgcn_mfma_f32_16x16x32_bf16(eh, cl, lacc, 0, 0, 0);
    }
    float* lg_out = out + O3 + (size_t)blk * (KK * NN);
    float* ag_out = out + O1 + (size_t)blk * (KK * NN);
#pragma unroll
    for (int r = 0; r < 4; ++r) {
      const int row = mrow + l4 * 4 + r;
      float lg = lacc[r] * 10.0f;
      float mx = lg;
#pragma unroll
      for (int m = 1; m < 16; m <<= 1) mx = fmaxf(mx, __shfl_xor(mx, m));
      float p = __expf(lg - mx);
      float s = p;
#pragma unroll
      for (int m = 1; m < 16; m <<= 1) s += __shfl_xor(s, m);
      float a = p / s;
      lg_out[row * 16 + l15] = lg;
      ag_out[row * 16 + l15] = a;
      sAlp[row][l15] = a;
    }
  }
  __syncthreads();

  // ---- Phase M: m = alpha @ cb (VALU; cb from L1) ----
  {
    const int pg = tid >> 5;
    const int cg = tid & 31;
    const float4* cb4 = (const float4*)cb;  // [n][32]
    float4 mac0 = make_float4(0.f, 0.f, 0.f, 0.f);
    float4 mac1 = mac0, mac2 = mac0, mac3 = mac0;
#pragma unroll
    for (int n = 0; n < 16; ++n) {
      float4 cv = cb4[n * 32 + cg];
      float a0 = sAlp[pg * 4 + 0][n];
      float a1 = sAlp[pg * 4 + 1][n];
      float a2 = sAlp[pg * 4 + 2][n];
      float a3 = sAlp[pg * 4 + 3][n];
      mac0.x += a0 * cv.x; mac0.y += a0 * cv.y; mac0.z += a0 * cv.z; mac0.w += a0 * cv.w;
      mac1.x += a1 * cv.x; mac1.y += a1 * cv.y; mac1.z += a1 * cv.z; mac1.w += a1 * cv.w;
      mac2.x += a2 * cv.x; mac2.y += a2 * cv.y; mac2.z += a2 * cv.z; mac2.w += a2 * cv.w;
      mac3.x += a3 * cv.x; mac3.y += a3 * cv.y; mac3.z += a3 * cv.z; mac3.w += a3 * cv.w;
    }
    float* mg = out + O0 + (size_t)blk * (KK * DD);
    *(float4*)(mg + (size_t)(pg * 4 + 0) * 128 + cg * 4) = mac0;
    *(float4*)(mg + (size_t)(pg * 4 + 1) * 128 + cg * 4) = mac1;
    *(float4*)(mg + (size_t)(pg * 4 + 2) * 128 + cg * 4) = mac2;
    *(float4*)(mg + (size_t)(pg * 4 + 3) * 128 + cg * 4) = mac3;
  }
}

extern "C" void kernel_launch(void* const* d_in, const int* in_sizes, int n_in,
                              void* d_out, int out_size, void* d_ws, size_t ws_size,
                              hipStream_t stream) {
  const float* z  = (const float*)d_in[0];   // (256,32,128)
  const float* W1 = (const float*)d_in[1];   // (256,256)
  const float* b1 = (const float*)d_in[2];   // (256,)
  const float* W2 = (const float*)d_in[3];   // (256,128)
  const float* b2 = (const float*)d_in[4];   // (128,)
  const float* cb = (const float*)d_in[5];   // (16,128)
  float* out = (float*)d_out;

  // ws: Hcat fp32 [8192][512] | zb | W1th | W1tl | Wh | Wl | cbh | cbl (~18.4MB)
  float* Hcat = (float*)d_ws;
  short* zb   = (short*)(Hcat + (size_t)8192 * 512);
  short* W1th = zb + (size_t)1048576;
  short* W1tl = W1th + (size_t)65536;
  short* Wh   = W1tl + (size_t)65536;
  short* Wl   = Wh + (size_t)32768;
  short* cbh  = Wl + (size_t)32768;
  short* cbl  = cbh + (size_t)2048;

  prep_kernel<<<4096, 256, 0, stream>>>(z, W1, W2, cb, zb, W1th, W1tl, Wh, Wl, cbh, cbl);
  hproj_mfma<<<dim3(256, 4), 256, 0, stream>>>(zb, W1th, W1tl, Hcat);
  pair_kernel<<<BB * KK, 256, 0, stream>>>(Hcat, b1, Wh, Wl, b2, cb, cbh, cbl, out);
}